// Round 5
// baseline (345.271 us; speedup 1.0000x reference)
//
#include <hip/hip_runtime.h>
#include <math.h>

#define B_ 16
#define S_ 2048
#define DM_ 64
#define HD_ 1024

typedef float floatx4 __attribute__((ext_vector_type(4)));
typedef short bf16x8 __attribute__((ext_vector_type(8)));
typedef unsigned short ushort4v __attribute__((ext_vector_type(4)));
typedef unsigned short ushort8v __attribute__((ext_vector_type(8)));

// ---------------------------------------------------------------------------
// Algebraic refactor (unchanged):
//   logits = (x Wq)(x Wk)^T = x M x^T,  M = Wq Wk^T (64x64)
//   out    = softmax(mask(logits/4)) @ (x Wv) = (P @ x) @ Wv
//
// R5: kill per-tile staging + barriers. R4's k_fused spent its time on VALU
// cvt4 staging (~128 inst/thread/tile) + 2 barriers/tile at 1 block/CU.
// Fix: k_prep precomputes the split-bf16 forms of x ONCE:
//   xh/xl  row-major [16][2048][64]  (QK's B-frags = contiguous row segments
//                                     of x; also y-GEMM's A-frags)
//   xTh/xTl d-major  [16][64][2048]  (PX's B-frags = contiguous xT rows)
// Main loop reads B-frags directly from global (32 MB, L3-resident, 4-wave
// L1 reuse) -> NO x staging, NO main-loop barriers (P is wave-private).
// LDS 110.6 KB -> 43 KB -> __launch_bounds__(512,4) = 2 blocks/CU; all 512
// blocks co-resident (4096 waves = 256 CU x 16): two-round serialization gone.
// Numerics bit-identical to R4 (same splits, same MFMA order): absmax 0.03125.
// ws (shorts): Mfh[4096] Mfl[4096] Wfh[65536] Wfl[65536]
//              xh[2M]@139264 xl@+2M xTh@+4M xTl@+6M   (~16.3 MB < prior 16.8)
// ---------------------------------------------------------------------------

__device__ __forceinline__ unsigned short bf_hi(float f) {
    return (unsigned short)((__float_as_uint(f) + 0x8000u) >> 16);   // RNE-ish
}
__device__ __forceinline__ float bf_f(unsigned short h) {
    return __uint_as_float((unsigned)h << 16);
}
__device__ __forceinline__ void cvt4(floatx4 v, ushort4v& h, ushort4v& l) {
    h[0] = bf_hi(v.x); l[0] = bf_hi(v.x - bf_f(h[0]));
    h[1] = bf_hi(v.y); l[1] = bf_hi(v.y - bf_f(h[1]));
    h[2] = bf_hi(v.z); l[2] = bf_hi(v.z - bf_f(h[2]));
    h[3] = bf_hi(v.w); l[3] = bf_hi(v.w - bf_f(h[3]));
}

#define MFMA(a, b, c) __builtin_amdgcn_mfma_f32_16x16x32_bf16((a), (b), (c), 0, 0, 0)

// frag-linear index for a B operand element (k, col):
//   idx = ((ct*2+kc)*64 + 16*lg+lm)*8 + j
__device__ __forceinline__ int fragidx(int k, int col) {
    return (((col >> 4) * 2 + (k >> 5)) * 64 + ((k >> 3) & 3) * 16 + (col & 15)) * 8
           + (k & 7);
}

// K1: prep.
//   bid 0..15  : M = Wq Wk^T -> frag-linear split bf16 (4 d-rows per block)
//   bid 16..19 : Wv -> frag-linear split bf16 (256 cols per block)
//   bid 20..531: x -> xh/xl (row-major) + xTh/xTl (d-major), split bf16
__global__ __launch_bounds__(256) void k_prep(
        const float* __restrict__ x, const float* __restrict__ W,
        unsigned short* __restrict__ ws) {
    unsigned short* Mfh = ws;
    unsigned short* Mfl = ws + 4096;
    unsigned short* Wfh = ws + 8192;
    unsigned short* Wfl = ws + 73728;
    unsigned short* xh  = ws + 139264;
    unsigned short* xl  = xh + 2097152;
    unsigned short* xTh = xl + 2097152;
    unsigned short* xTl = xTh + 2097152;
    const int bid = blockIdx.x, t = threadIdx.x;
    if (bid < 16) {
        const int d = bid * 4 + (t >> 6);   // k-axis of y = x@M
        const int e = t & 63;               // col
        const floatx4* wq = (const floatx4*)(W + (size_t)d * 3072);
        const floatx4* wk = (const floatx4*)(W + (size_t)e * 3072 + 1024);
        floatx4 a = {0.f, 0.f, 0.f, 0.f};
#pragma unroll 4
        for (int j = 0; j < 256; ++j) {
            floatx4 qv = wq[j], kv = wk[j];
            a.x = fmaf(qv.x, kv.x, a.x);
            a.y = fmaf(qv.y, kv.y, a.y);
            a.z = fmaf(qv.z, kv.z, a.z);
            a.w = fmaf(qv.w, kv.w, a.w);
        }
        const float v = (a.x + a.y) + (a.z + a.w);
        const int idx = fragidx(d, e);
        const unsigned short hv = bf_hi(v);
        Mfh[idx] = hv;
        Mfl[idx] = bf_hi(v - bf_f(hv));
    } else if (bid < 20) {
        const int col = (bid - 16) * 256 + t;   // 0..1023, lanes coalesced
#pragma unroll 8
        for (int k = 0; k < 64; ++k) {
            const float v = W[(size_t)k * 3072 + 2048 + col];
            const int idx = fragidx(k, col);
            const unsigned short hv = bf_hi(v);
            Wfh[idx] = hv;
            Wfl[idx] = bf_hi(v - bf_f(hv));
        }
    } else {
        const int xbid = bid - 20;              // 0..511
        const int bb = xbid >> 5, rb = xbid & 31;
        const int kg = t >> 4, dc = t & 15;     // 4 rows x 4 cols per thread
        const size_t r0 = (size_t)bb * S_ + rb * 64;
        const float* sp = x + (r0 + kg * 4) * 64 + dc * 4;
        floatx4 v0 = *(const floatx4*)(sp);
        floatx4 v1 = *(const floatx4*)(sp + 64);
        floatx4 v2 = *(const floatx4*)(sp + 128);
        floatx4 v3 = *(const floatx4*)(sp + 192);
        ushort4v h0, l0, h1, l1, h2, l2, h3, l3;
        cvt4(v0, h0, l0); cvt4(v1, h1, l1);
        cvt4(v2, h2, l2); cvt4(v3, h3, l3);
        const size_t ro = (r0 + kg * 4) * 64 + dc * 4;
        *(ushort4v*)(xh + ro)       = h0;
        *(ushort4v*)(xh + ro + 64)  = h1;
        *(ushort4v*)(xh + ro + 128) = h2;
        *(ushort4v*)(xh + ro + 192) = h3;
        *(ushort4v*)(xl + ro)       = l0;
        *(ushort4v*)(xl + ro + 64)  = l1;
        *(ushort4v*)(xl + ro + 128) = l2;
        *(ushort4v*)(xl + ro + 192) = l3;
#pragma unroll
        for (int e = 0; e < 4; ++e) {
            ushort4v th = {h0[e], h1[e], h2[e], h3[e]};   // keys 4kg..+3 @ d=4dc+e
            ushort4v tl = {l0[e], l1[e], l2[e], l3[e]};
            const size_t to = ((size_t)bb * 64 + dc * 4 + e) * 2048 + rb * 64 + kg * 4;
            *(ushort4v*)(xTh + to) = th;
            *(ushort4v*)(xTl + to) = tl;
        }
    }
}

// K2: fused y-GEMM + flash attention + out-GEMM.
// 512 thr = 2 split-K halves of 4 waves; wave w (in half) owns q rows 16w..+15.
// Main loop: barrier-free (x B-frags from global, P wave-private).
__global__ __launch_bounds__(512, 4) void k_fused(
        const unsigned short* __restrict__ wsf, float* __restrict__ out) {
    // shorts: yh[4608] yl[4608] P[8*1152]; merge overlays: scratch floats
    // 0..6143 (shorts 0..12287), Unh @12288, Unl @16896. 21504 sh = 43,008 B.
    __shared__ __align__(16) unsigned short sm[21504];

    const int tid  = threadIdx.x;
    const int h    = tid >> 8;
    const int lt   = tid & 255;
    const int w    = lt >> 6;            // wave in half 0..3
    const int wid  = tid >> 6;           // wave in block 0..7
    const int lane = tid & 63;
    const int lm   = lane & 15;
    const int lg   = lane >> 4;

    const int bid = blockIdx.x;
    const int qt  = bid >> 4;            // heavy-first
    const int bb  = bid & 15;
    const int q0  = qt * 64;
    const int T   = 32 - qt;
    const int nA  = (T + 1) >> 1;
    const int nOwn = h ? (T - nA) : nA;
    const int kt0  = q0 + (h ? nA * 64 : 0);

    unsigned short* yh = sm;
    unsigned short* yl = sm + 4608;
    unsigned short* Pw = sm + 9216 + wid * 1152;   // per-wave P [16][72]

    const unsigned short* Mfh = wsf;
    const unsigned short* Mfl = wsf + 4096;
    const unsigned short* Wfh = wsf + 8192;
    const unsigned short* Wfl = wsf + 73728;
    const unsigned short* xh  = wsf + 139264;
    const unsigned short* xl  = xh + 2097152;
    const unsigned short* xTh = xl + 2097152;
    const unsigned short* xTl = xTh + 2097152;

    // ---- y prologue: y = xq @ M, 3-term, all 8 waves ----
    // wave wid: row-tile rt=wid&3, col-tiles {2*(wid>>2), 2*(wid>>2)+1}
    {
        const int rt = wid & 3;
        const int cp = wid >> 2;
        bf16x8 axh[2], axl[2];
#pragma unroll
        for (int kc = 0; kc < 2; ++kc) {
            const size_t off =
                ((size_t)bb * S_ + q0 + 16 * rt + lm) * 64 + 32 * kc + 8 * lg;
            axh[kc] = *(const bf16x8*)(xh + off);
            axl[kc] = *(const bf16x8*)(xl + off);
        }
#pragma unroll
        for (int cc = 0; cc < 2; ++cc) {
            const int ct = cp * 2 + cc;
            floatx4 yC = {0.f, 0.f, 0.f, 0.f};
#pragma unroll
            for (int kc = 0; kc < 2; ++kc) {
                bf16x8 bh = *(const bf16x8*)(Mfh + ((ct * 2 + kc) * 64 + lane) * 8);
                bf16x8 bl = *(const bf16x8*)(Mfl + ((ct * 2 + kc) * 64 + lane) * 8);
                yC = MFMA(axh[kc], bh, yC);
                yC = MFMA(axh[kc], bl, yC);
                yC = MFMA(axl[kc], bh, yC);
            }
#pragma unroll
            for (int r = 0; r < 4; ++r) {
                const float vv = yC[r];
                const unsigned short hv = bf_hi(vv);
                const int o = (16 * rt + 4 * lg + r) * 72 + ct * 16 + lm;
                yh[o] = hv;
                yl[o] = bf_hi(vv - bf_f(hv));
            }
        }
    }
    __syncthreads();   // y visible

    // hoist y A-frags (loop-invariant): rows 16w+lm
    bf16x8 aqh[2], aql[2];
#pragma unroll
    for (int kc = 0; kc < 2; ++kc) {
        const int off = (16 * w + lm) * 72 + 32 * kc + 8 * lg;
        aqh[kc] = *(const bf16x8*)(yh + off);
        aql[kc] = *(const bf16x8*)(yl + off);
    }

    // per-thread invariant global B-frag bases
    const unsigned short* xqh = xh + ((size_t)bb * S_ + lm) * 64 + lg * 8;
    const unsigned short* xql = xl + ((size_t)bb * S_ + lm) * 64 + lg * 8;
    const unsigned short* xth = xTh + ((size_t)bb * 64 + lm) * 2048 + lg * 8;
    const unsigned short* xtl = xTl + ((size_t)bb * 64 + lm) * 2048 + lg * 8;

    floatx4 U[4];                 // U[c][r] = U[q=4lg+r][d=lm+16c]
    float m[4], lsum[4];
#pragma unroll
    for (int r = 0; r < 4; ++r) { m[r] = -INFINITY; lsum[r] = 0.f; }
#pragma unroll
    for (int c = 0; c < 4; ++c) U[c] = (floatx4){0.f, 0.f, 0.f, 0.f};

    for (int t = 0; t < nOwn; ++t) {
        const int kt = kt0 + t * 64;

        // ---- QK: 3-term split, 24 mfma; B-frags direct from global xh/xl ----
        floatx4 Sc[4] = {{0.f,0.f,0.f,0.f},{0.f,0.f,0.f,0.f},
                         {0.f,0.f,0.f,0.f},{0.f,0.f,0.f,0.f}};
#pragma unroll
        for (int kc = 0; kc < 2; ++kc) {
#pragma unroll
            for (int c = 0; c < 4; ++c) {
                const size_t o = (size_t)kt * 64 + c * 1024 + kc * 32;
                bf16x8 bh = *(const bf16x8*)(xqh + o);
                bf16x8 bl = *(const bf16x8*)(xql + o);
                Sc[c] = MFMA(aqh[kc], bh, Sc[c]);
                Sc[c] = MFMA(aqh[kc], bl, Sc[c]);
                Sc[c] = MFMA(aql[kc], bh, Sc[c]);
            }
        }

        // ---- scale + faithful mask + online softmax ----
        const bool diag = (kt == q0);   // wave-uniform; only half A's tile 0
        float p[4][4], alpha[4];
#pragma unroll
        for (int r = 0; r < 4; ++r) {
            const int ig = q0 + 16 * w + 4 * lg + r;
            float sv[4];
            float rmax = -INFINITY;
#pragma unroll
            for (int c = 0; c < 4; ++c) {
                float v = Sc[c][r] * 0.25f;
                bool dead = (v == 0.0f);                  // faithful ==0 quirk
                if (diag) dead = dead || ((kt + lm + 16 * c) < ig);   // triu
                if (dead) v = -9.0e15f;
                sv[c] = v;
                rmax = fmaxf(rmax, v);
            }
            rmax = fmaxf(rmax, __shfl_xor(rmax, 1));
            rmax = fmaxf(rmax, __shfl_xor(rmax, 2));
            rmax = fmaxf(rmax, __shfl_xor(rmax, 4));
            rmax = fmaxf(rmax, __shfl_xor(rmax, 8));
            const float mnew = fmaxf(m[r], rmax);
            alpha[r] = __expf(m[r] - mnew);               // first tile: 0
            float ps = 0.f;
#pragma unroll
            for (int c = 0; c < 4; ++c) {
                const float pv = __expf(sv[c] - mnew);
                p[r][c] = pv;
                ps += pv;
            }
            m[r] = mnew;
            lsum[r] = lsum[r] * alpha[r] + ps;            // per-lane partial
        }

        // P -> per-wave LDS (bf16 hi); same-wave RAW handled by lgkmcnt
#pragma unroll
        for (int r = 0; r < 4; ++r)
#pragma unroll
            for (int c = 0; c < 4; ++c)
                Pw[(4 * lg + r) * 72 + lm + 16 * c] = bf_hi(p[r][c]);

        // rescale U
        floatx4 av = {alpha[0], alpha[1], alpha[2], alpha[3]};
#pragma unroll
        for (int c = 0; c < 4; ++c) U[c] *= av;

        // ---- PX: 2-term, 16 mfma; B-frags direct from global xTh/xTl ----
#pragma unroll
        for (int kc = 0; kc < 2; ++kc) {
            bf16x8 ap = *(const bf16x8*)(Pw + lm * 72 + 32 * kc + 8 * lg);
#pragma unroll
            for (int c = 0; c < 4; ++c) {
                const size_t o = (size_t)c * 32768 + kt + kc * 32;
                bf16x8 bh = *(const bf16x8*)(xth + o);
                bf16x8 bl = *(const bf16x8*)(xtl + o);
                U[c] = MFMA(ap, bh, U[c]);
                U[c] = MFMA(ap, bl, U[c]);
            }
        }
    }

    // ---- finalize per-half l ----
    float lf[4];
#pragma unroll
    for (int r = 0; r < 4; ++r) {
        float s2 = lsum[r];
        s2 += __shfl_xor(s2, 1);
        s2 += __shfl_xor(s2, 2);
        s2 += __shfl_xor(s2, 4);
        s2 += __shfl_xor(s2, 8);
        lf[r] = s2;
    }

    // ---- merge halves; half A writes Un (split bf16) into LDS ----
    __syncthreads();                       // all compute done; y/P dead
    float* sc = (float*)sm;                // 256*24 floats (shorts 0..12287)
    unsigned short* Unh = sm + 12288;
    unsigned short* Unl = sm + 16896;
    if (h == 1) {
        float* bp = sc + lt * 24;
        *(floatx4*)(bp)     = (floatx4){m[0], m[1], m[2], m[3]};
        *(floatx4*)(bp + 4) = (floatx4){lf[0], lf[1], lf[2], lf[3]};
#pragma unroll
        for (int c = 0; c < 4; ++c) *(floatx4*)(bp + 8 + 4 * c) = U[c];
    }
    __syncthreads();
    if (h == 0) {
        const float* bp = sc + lt * 24;
        floatx4 mB = *(const floatx4*)(bp);
        floatx4 lB = *(const floatx4*)(bp + 4);
        floatx4 UB[4];
#pragma unroll
        for (int c = 0; c < 4; ++c) UB[c] = *(const floatx4*)(bp + 8 + 4 * c);
        float eA[4], eB[4], inv[4];
#pragma unroll
        for (int r = 0; r < 4; ++r) {
            const float mT = fmaxf(m[r], mB[r]);   // m finite (A has tile 0)
            eA[r] = __expf(m[r] - mT);
            eB[r] = __expf(mB[r] - mT);            // empty B: exp(-inf)=0
            const float lT = lf[r] * eA[r] + lB[r] * eB[r];
            inv[r] = 1.0f / lT;
        }
#pragma unroll
        for (int r = 0; r < 4; ++r)
#pragma unroll
            for (int c = 0; c < 4; ++c) {
                const float o = (U[c][r] * eA[r] + UB[c][r] * eB[r]) * inv[r];
                const unsigned short hv = bf_hi(o);
                const int oo = (16 * w + 4 * lg + r) * 72 + lm + 16 * c;
                Unh[oo] = hv;
                Unl[oo] = bf_hi(o - bf_f(hv));
            }
    }
    __syncthreads();   // Un visible

    // ---- out-GEMM: out = Un @ Wv, 3-term, all 8 waves ----
    bf16x8 Ah[4][2], Al[4][2];
#pragma unroll
    for (int rt = 0; rt < 4; ++rt)
#pragma unroll
        for (int kc = 0; kc < 2; ++kc) {
            const int off = (16 * rt + lm) * 72 + 32 * kc + 8 * lg;
            Ah[rt][kc] = *(const bf16x8*)(Unh + off);
            Al[rt][kc] = *(const bf16x8*)(Unl + off);
        }
    const size_t orow0 = (size_t)bb * S_ + q0;
#pragma unroll
    for (int ctl = 0; ctl < 8; ++ctl) {
        const int ct = wid * 8 + ctl;
        bf16x8 Bh0 = *(const bf16x8*)(Wfh + ((ct * 2 + 0) * 64 + lane) * 8);
        bf16x8 Bl0 = *(const bf16x8*)(Wfl + ((ct * 2 + 0) * 64 + lane) * 8);
        bf16x8 Bh1 = *(const bf16x8*)(Wfh + ((ct * 2 + 1) * 64 + lane) * 8);
        bf16x8 Bl1 = *(const bf16x8*)(Wfl + ((ct * 2 + 1) * 64 + lane) * 8);
#pragma unroll
        for (int rt = 0; rt < 4; ++rt) {
            floatx4 C = {0.f, 0.f, 0.f, 0.f};
            C = MFMA(Ah[rt][0], Bh0, C);
            C = MFMA(Ah[rt][0], Bl0, C);
            C = MFMA(Al[rt][0], Bh0, C);
            C = MFMA(Ah[rt][1], Bh1, C);
            C = MFMA(Ah[rt][1], Bl1, C);
            C = MFMA(Al[rt][1], Bh1, C);
#pragma unroll
            for (int r = 0; r < 4; ++r)
                out[(orow0 + 16 * rt + 4 * lg + r) * HD_ + ct * 16 + lm] = C[r];
        }
    }
}

extern "C" void kernel_launch(void* const* d_in, const int* in_sizes, int n_in,
                              void* d_out, int out_size, void* d_ws, size_t ws_size,
                              hipStream_t stream) {
    const float* x = (const float*)d_in[0];
    const float* W = (const float*)d_in[1];
    unsigned short* wsf = (unsigned short*)d_ws;   // ~16.3 MB used

    k_prep <<<dim3(532), 256, 0, stream>>>(x, W, wsf);
    k_fused<<<dim3(512), 512, 0, stream>>>(wsf, (float*)d_out);
}

// Round 7
// 217.238 us; speedup vs baseline: 1.5894x; 1.5894x over previous
//
#include <hip/hip_runtime.h>
#include <math.h>

#define B_ 16
#define S_ 2048
#define DM_ 64
#define HD_ 1024

typedef float floatx4 __attribute__((ext_vector_type(4)));
typedef short bf16x8 __attribute__((ext_vector_type(8)));
typedef unsigned short ushort4v __attribute__((ext_vector_type(4)));
typedef unsigned short ushort8v __attribute__((ext_vector_type(8)));

// ---------------------------------------------------------------------------
// logits = x M x^T (M = Wq Wk^T), out = softmax(mask(logits/4)) @ (P x) @ Wv
//
// R7 = R6 structure + QK precision restored (R6 failed absmax 0.152 > 0.139).
// Error attribution: QK's dropped y*xl term (y~N(0,16) amplifies x's bf16
// residual; logit err ~0.008 -> out tail ~0.12). PX 1-term error is BOUNDED:
// |sum p_j xl_j| <= max|xl| ~ 0.01 (convex comb) -> keep PX 1-term.
//   * QK back to 3-term (yh*xh + yl*xh + yh*xl) = R2/R4 verified numerics.
//   * xrl buffer paid for by LDS OVERLAY: y-tile (yh/yl) is dead after the
//     A-frag hoist; P buffers are first written 2 barriers later -> P
//     overlays y. LDS stays 73,728 B -> 2 blocks/CU, 512 blocks co-resident.
//   * staging = 6 pure b128 copies/thread/tile (xr hi+lo, xt hi), register
//     prefetch of tile t+1 in flight across QK+softmax+PX (R4's scheme).
//   * bid remap pairs heavy qt with light 31-qt per CU slot.
// ws (shorts): Mfh[4096] Mfl[4096] Wfh[65536] Wfl[65536]
//              xh[2M]@139264 xl@+2M xTh@+4M   (~12.9 MB)
// ---------------------------------------------------------------------------

__device__ __forceinline__ unsigned short bf_hi(float f) {
    return (unsigned short)((__float_as_uint(f) + 0x8000u) >> 16);   // RNE-ish
}
__device__ __forceinline__ float bf_f(unsigned short h) {
    return __uint_as_float((unsigned)h << 16);
}
__device__ __forceinline__ void cvt4(floatx4 v, ushort4v& h, ushort4v& l) {
    h[0] = bf_hi(v.x); l[0] = bf_hi(v.x - bf_f(h[0]));
    h[1] = bf_hi(v.y); l[1] = bf_hi(v.y - bf_f(h[1]));
    h[2] = bf_hi(v.z); l[2] = bf_hi(v.z - bf_f(h[2]));
    h[3] = bf_hi(v.w); l[3] = bf_hi(v.w - bf_f(h[3]));
}

#define MFMA(a, b, c) __builtin_amdgcn_mfma_f32_16x16x32_bf16((a), (b), (c), 0, 0, 0)

// frag-linear index for a B operand element (k, col):
//   idx = ((ct*2+kc)*64 + 16*lg+lm)*8 + j
__device__ __forceinline__ int fragidx(int k, int col) {
    return (((col >> 4) * 2 + (k >> 5)) * 64 + ((k >> 3) & 3) * 16 + (col & 15)) * 8
           + (k & 7);
}

// K1: prep.
//   bid 0..15  : M = Wq Wk^T -> frag-linear split bf16
//   bid 16..19 : Wv -> frag-linear split bf16
//   bid 20..531: x -> xh/xl (row-major) + xTh (d-major, hi only)
__global__ __launch_bounds__(256) void k_prep(
        const float* __restrict__ x, const float* __restrict__ W,
        unsigned short* __restrict__ ws) {
    unsigned short* Mfh = ws;
    unsigned short* Mfl = ws + 4096;
    unsigned short* Wfh = ws + 8192;
    unsigned short* Wfl = ws + 73728;
    unsigned short* xh  = ws + 139264;
    unsigned short* xl  = xh + 2097152;
    unsigned short* xTh = xl + 2097152;
    const int bid = blockIdx.x, t = threadIdx.x;
    if (bid < 16) {
        const int d = bid * 4 + (t >> 6);
        const int e = t & 63;
        const floatx4* wq = (const floatx4*)(W + (size_t)d * 3072);
        const floatx4* wk = (const floatx4*)(W + (size_t)e * 3072 + 1024);
        floatx4 a = {0.f, 0.f, 0.f, 0.f};
#pragma unroll 4
        for (int j = 0; j < 256; ++j) {
            floatx4 qv = wq[j], kv = wk[j];
            a.x = fmaf(qv.x, kv.x, a.x);
            a.y = fmaf(qv.y, kv.y, a.y);
            a.z = fmaf(qv.z, kv.z, a.z);
            a.w = fmaf(qv.w, kv.w, a.w);
        }
        const float v = (a.x + a.y) + (a.z + a.w);
        const int idx = fragidx(d, e);
        const unsigned short hv = bf_hi(v);
        Mfh[idx] = hv;
        Mfl[idx] = bf_hi(v - bf_f(hv));
    } else if (bid < 20) {
        const int col = (bid - 16) * 256 + t;
#pragma unroll 8
        for (int k = 0; k < 64; ++k) {
            const float v = W[(size_t)k * 3072 + 2048 + col];
            const int idx = fragidx(k, col);
            const unsigned short hv = bf_hi(v);
            Wfh[idx] = hv;
            Wfl[idx] = bf_hi(v - bf_f(hv));
        }
    } else {
        const int xbid = bid - 20;              // 0..511
        const int bb = xbid >> 5, rb = xbid & 31;
        const int kg = t >> 4, dc = t & 15;     // 4 rows x 4 cols per thread
        const size_t r0 = (size_t)bb * S_ + rb * 64;
        const float* sp = x + (r0 + kg * 4) * 64 + dc * 4;
        floatx4 v0 = *(const floatx4*)(sp);
        floatx4 v1 = *(const floatx4*)(sp + 64);
        floatx4 v2 = *(const floatx4*)(sp + 128);
        floatx4 v3 = *(const floatx4*)(sp + 192);
        ushort4v h0, l0, h1, l1, h2, l2, h3, l3;
        cvt4(v0, h0, l0); cvt4(v1, h1, l1);
        cvt4(v2, h2, l2); cvt4(v3, h3, l3);
        const size_t ro = (r0 + kg * 4) * 64 + dc * 4;
        *(ushort4v*)(xh + ro)       = h0;
        *(ushort4v*)(xh + ro + 64)  = h1;
        *(ushort4v*)(xh + ro + 128) = h2;
        *(ushort4v*)(xh + ro + 192) = h3;
        *(ushort4v*)(xl + ro)       = l0;
        *(ushort4v*)(xl + ro + 64)  = l1;
        *(ushort4v*)(xl + ro + 128) = l2;
        *(ushort4v*)(xl + ro + 192) = l3;
#pragma unroll
        for (int e = 0; e < 4; ++e) {
            ushort4v th = {h0[e], h1[e], h2[e], h3[e]};   // keys 4kg..+3 @ d
            const size_t to = ((size_t)bb * 64 + dc * 4 + e) * 2048 + rb * 64 + kg * 4;
            *(ushort4v*)(xTh + to) = th;
        }
    }
}

// K2: fused y-GEMM + flash attention + out-GEMM.
// 512 thr = 2 split-K halves of 4 waves; wave w (in half) owns q rows 16w..+15.
// LDS 73,728 B (P overlays y) -> 2 blocks/CU.
__global__ __launch_bounds__(512, 4) void k_fused(
        const unsigned short* __restrict__ wsf, float* __restrict__ out) {
    // shorts: xrh 2x4608 @0, xrl 2x4608 @9216, xth 2x4608 @18432,
    // y/P overlay @27648: {yh @27648, yl @32256} then P 8x1152 @27648.
    // Merge overlay: scratch floats @0 (12288 sh), Unh @12288, Unl @16896.
    __shared__ __align__(16) unsigned short sm[36864];

    const int tid  = threadIdx.x;
    const int h    = tid >> 8;
    const int lt   = tid & 255;
    const int w    = lt >> 6;            // wave in half 0..3
    const int wid  = tid >> 6;           // wave in block 0..7
    const int lane = tid & 63;
    const int lm   = lane & 15;
    const int lg   = lane >> 4;

    // bid remap: first 256 heavy (qt 0..15), second 256 light (qt 31..16).
    const int bi = blockIdx.x;
    int qt, bb;
    if (bi < 256) { qt = bi >> 4;                bb = bi & 15; }
    else          { qt = 31 - ((bi - 256) >> 4); bb = (bi - 256) & 15; }
    const int q0 = qt * 64;
    const int T  = 32 - qt;
    const int nA = (T + 1) >> 1;
    const int nOwn = h ? (T - nA) : nA;
    const int kt0  = q0 + (h ? nA * 64 : 0);

    unsigned short* xrh = sm + h * 4608;            // [key][72] hi
    unsigned short* xrl = sm + 9216 + h * 4608;     // [key][72] lo
    unsigned short* xth = sm + 18432 + h * 4608;    // [d][72] hi
    unsigned short* Pw  = sm + 27648 + wid * 1152;  // per-wave P (overlays y)
    unsigned short* yh  = sm + 27648;
    unsigned short* yl  = sm + 32256;

    const unsigned short* Mfh = wsf;
    const unsigned short* Mfl = wsf + 4096;
    const unsigned short* Wfh = wsf + 8192;
    const unsigned short* Wfl = wsf + 73728;
    const unsigned short* xh  = wsf + 139264;
    const unsigned short* xl  = xh + 2097152;
    const unsigned short* xTh = xl + 2097152;

    // ---- y prologue: y = xq @ M, 3-term, all 8 waves ----
    {
        const int rt = wid & 3;
        const int cp = wid >> 2;
        bf16x8 axh[2], axl[2];
#pragma unroll
        for (int kc = 0; kc < 2; ++kc) {
            const size_t off =
                ((size_t)bb * S_ + q0 + 16 * rt + lm) * 64 + 32 * kc + 8 * lg;
            axh[kc] = *(const bf16x8*)(xh + off);
            axl[kc] = *(const bf16x8*)(xl + off);
        }
#pragma unroll
        for (int cc = 0; cc < 2; ++cc) {
            const int ct = cp * 2 + cc;
            floatx4 yC = {0.f, 0.f, 0.f, 0.f};
#pragma unroll
            for (int kc = 0; kc < 2; ++kc) {
                bf16x8 bh = *(const bf16x8*)(Mfh + ((ct * 2 + kc) * 64 + lane) * 8);
                bf16x8 bl = *(const bf16x8*)(Mfl + ((ct * 2 + kc) * 64 + lane) * 8);
                yC = MFMA(axh[kc], bh, yC);
                yC = MFMA(axh[kc], bl, yC);
                yC = MFMA(axl[kc], bh, yC);
            }
#pragma unroll
            for (int r = 0; r < 4; ++r) {
                const float vv = yC[r];
                const unsigned short hv = bf_hi(vv);
                const int o = (16 * rt + 4 * lg + r) * 72 + ct * 16 + lm;
                yh[o] = hv;
                yl[o] = bf_hi(vv - bf_f(hv));
            }
        }
    }
    __syncthreads();   // y visible

    // hoist y A-frags (loop-invariant): rows 16w+lm. After this, y is dead;
    // P overlays it (first P write is 2 barriers later).
    bf16x8 aqh[2], aql[2];
#pragma unroll
    for (int kc = 0; kc < 2; ++kc) {
        const int off = (16 * w + lm) * 72 + 32 * kc + 8 * lg;
        aqh[kc] = *(const bf16x8*)(yh + off);
        aql[kc] = *(const bf16x8*)(yl + off);
    }

    // staging roles: row srow (key row for xr, d row for xt), 16-short part
    const int srow = lt >> 2, spart = lt & 3;

    // prefetch tile 0 into registers (pure copies; 6 x b128)
    ushort8v p0, p1, p2, p3, p4, p5;
    if (0 < nOwn) {
        const size_t ro = ((size_t)bb * S_ + kt0 + srow) * 64 + spart * 16;
        const unsigned short* s3 =
            xTh + ((size_t)bb * 64 + srow) * 2048 + kt0 + spart * 16;
        p0 = *(const ushort8v*)(xh + ro); p1 = *(const ushort8v*)(xh + ro + 8);
        p2 = *(const ushort8v*)(xl + ro); p3 = *(const ushort8v*)(xl + ro + 8);
        p4 = *(const ushort8v*)(s3);      p5 = *(const ushort8v*)(s3 + 8);
    }

    floatx4 U[4];                 // U[c][r] = U[q=4lg+r][d=lm+16c]
    float m[4], lsum[4];
#pragma unroll
    for (int r = 0; r < 4; ++r) { m[r] = -INFINITY; lsum[r] = 0.f; }
#pragma unroll
    for (int c = 0; c < 4; ++c) U[c] = (floatx4){0.f, 0.f, 0.f, 0.f};

    for (int t = 0; t < nA; ++t) {          // uniform bound: barriers for all
        const int kt = kt0 + t * 64;
        __syncthreads();   // prev tile readers done (also orders y-reads)
        if (t < nOwn) {
            const int o = srow * 72 + spart * 16;
            *(ushort8v*)(xrh + o)     = p0;
            *(ushort8v*)(xrh + o + 8) = p1;
            *(ushort8v*)(xrl + o)     = p2;
            *(ushort8v*)(xrl + o + 8) = p3;
            *(ushort8v*)(xth + o)     = p4;
            *(ushort8v*)(xth + o + 8) = p5;
        }
        __syncthreads();   // tile visible

        // prefetch next tile (in flight across QK+softmax+PX)
        if (t + 1 < nOwn) {
            const size_t ro = ((size_t)bb * S_ + kt + 64 + srow) * 64 + spart * 16;
            const unsigned short* s3 =
                xTh + ((size_t)bb * 64 + srow) * 2048 + kt + 64 + spart * 16;
            p0 = *(const ushort8v*)(xh + ro); p1 = *(const ushort8v*)(xh + ro + 8);
            p2 = *(const ushort8v*)(xl + ro); p3 = *(const ushort8v*)(xl + ro + 8);
            p4 = *(const ushort8v*)(s3);      p5 = *(const ushort8v*)(s3 + 8);
        }

        if (t < nOwn) {
            // ---- QK: 3-term (yh*xh + yl*xh + yh*xl), 24 mfma ----
            floatx4 Sc[4] = {{0.f,0.f,0.f,0.f},{0.f,0.f,0.f,0.f},
                             {0.f,0.f,0.f,0.f},{0.f,0.f,0.f,0.f}};
#pragma unroll
            for (int kc = 0; kc < 2; ++kc) {
#pragma unroll
                for (int c = 0; c < 4; ++c) {
                    const int ro = (lm + 16 * c) * 72 + 32 * kc + 8 * lg;
                    bf16x8 bh = *(const bf16x8*)(xrh + ro);
                    bf16x8 bl = *(const bf16x8*)(xrl + ro);
                    Sc[c] = MFMA(aqh[kc], bh, Sc[c]);
                    Sc[c] = MFMA(aql[kc], bh, Sc[c]);
                    Sc[c] = MFMA(aqh[kc], bl, Sc[c]);
                }
            }

            // ---- scale + faithful mask + online softmax ----
            const bool diag = (kt == q0);   // wave-uniform; half A tile 0 only
            float p[4][4], alpha[4];
#pragma unroll
            for (int r = 0; r < 4; ++r) {
                const int ig = q0 + 16 * w + 4 * lg + r;
                float sv[4];
                float rmax = -INFINITY;
#pragma unroll
                for (int c = 0; c < 4; ++c) {
                    float v = Sc[c][r] * 0.25f;
                    bool dead = (v == 0.0f);                  // faithful quirk
                    if (diag) dead = dead || ((kt + lm + 16 * c) < ig);  // triu
                    if (dead) v = -9.0e15f;
                    sv[c] = v;
                    rmax = fmaxf(rmax, v);
                }
                rmax = fmaxf(rmax, __shfl_xor(rmax, 1));
                rmax = fmaxf(rmax, __shfl_xor(rmax, 2));
                rmax = fmaxf(rmax, __shfl_xor(rmax, 4));
                rmax = fmaxf(rmax, __shfl_xor(rmax, 8));
                const float mnew = fmaxf(m[r], rmax);
                alpha[r] = __expf(m[r] - mnew);               // first tile: 0
                float ps = 0.f;
#pragma unroll
                for (int c = 0; c < 4; ++c) {
                    const float pv = __expf(sv[c] - mnew);
                    p[r][c] = pv;
                    ps += pv;
                }
                m[r] = mnew;
                lsum[r] = lsum[r] * alpha[r] + ps;            // per-lane partial
            }

            // P -> per-wave LDS (bf16 hi); same-wave RAW via lgkmcnt
#pragma unroll
            for (int r = 0; r < 4; ++r)
#pragma unroll
                for (int c = 0; c < 4; ++c)
                    Pw[(4 * lg + r) * 72 + lm + 16 * c] = bf_hi(p[r][c]);

            // rescale U
            floatx4 av = {alpha[0], alpha[1], alpha[2], alpha[3]};
#pragma unroll
            for (int c = 0; c < 4; ++c) U[c] *= av;

            // ---- PX: 1-term P_hi * xh, 8 mfma (bounded err <= max|xl|) ----
#pragma unroll
            for (int kc = 0; kc < 2; ++kc) {
                bf16x8 ap = *(const bf16x8*)(Pw + lm * 72 + 32 * kc + 8 * lg);
#pragma unroll
                for (int c = 0; c < 4; ++c) {
                    bf16x8 bh = *(const bf16x8*)(xth + (lm + 16 * c) * 72
                                                 + 32 * kc + 8 * lg);
                    U[c] = MFMA(ap, bh, U[c]);
                }
            }
        }
    }

    // ---- finalize per-half l ----
    float lf[4];
#pragma unroll
    for (int r = 0; r < 4; ++r) {
        float s2 = lsum[r];
        s2 += __shfl_xor(s2, 1);
        s2 += __shfl_xor(s2, 2);
        s2 += __shfl_xor(s2, 4);
        s2 += __shfl_xor(s2, 8);
        lf[r] = s2;
    }

    // ---- merge halves; half A writes Un (split bf16) into LDS ----
    __syncthreads();                       // all compute done; xr/xt/P dead
    float* sc = (float*)sm;                // 256*24 floats = shorts 0..12287
    unsigned short* Unh = sm + 12288;
    unsigned short* Unl = sm + 16896;
    if (h == 1) {
        float* bp = sc + lt * 24;
        *(floatx4*)(bp)     = (floatx4){m[0], m[1], m[2], m[3]};
        *(floatx4*)(bp + 4) = (floatx4){lf[0], lf[1], lf[2], lf[3]};
#pragma unroll
        for (int c = 0; c < 4; ++c) *(floatx4*)(bp + 8 + 4 * c) = U[c];
    }
    __syncthreads();
    if (h == 0) {
        const float* bp = sc + lt * 24;
        floatx4 mB = *(const floatx4*)(bp);
        floatx4 lB = *(const floatx4*)(bp + 4);
        floatx4 UB[4];
#pragma unroll
        for (int c = 0; c < 4; ++c) UB[c] = *(const floatx4*)(bp + 8 + 4 * c);
        float eA[4], eB[4], inv[4];
#pragma unroll
        for (int r = 0; r < 4; ++r) {
            const float mT = fmaxf(m[r], mB[r]);   // m finite (A has tile 0)
            eA[r] = __expf(m[r] - mT);
            eB[r] = __expf(mB[r] - mT);            // empty B: exp(-inf)=0
            const float lT = lf[r] * eA[r] + lB[r] * eB[r];
            inv[r] = 1.0f / lT;
        }
#pragma unroll
        for (int r = 0; r < 4; ++r)
#pragma unroll
            for (int c = 0; c < 4; ++c) {
                const float o = (U[c][r] * eA[r] + UB[c][r] * eB[r]) * inv[r];
                const unsigned short hv = bf_hi(o);
                const int oo = (16 * w + 4 * lg + r) * 72 + lm + 16 * c;
                Unh[oo] = hv;
                Unl[oo] = bf_hi(o - bf_f(hv));
            }
    }
    __syncthreads();   // Un visible

    // ---- out-GEMM: out = Un @ Wv, 3-term, all 8 waves ----
    bf16x8 Ah[4][2], Al[4][2];
#pragma unroll
    for (int rt = 0; rt < 4; ++rt)
#pragma unroll
        for (int kc = 0; kc < 2; ++kc) {
            const int off = (16 * rt + lm) * 72 + 32 * kc + 8 * lg;
            Ah[rt][kc] = *(const bf16x8*)(Unh + off);
            Al[rt][kc] = *(const bf16x8*)(Unl + off);
        }
    const size_t orow0 = (size_t)bb * S_ + q0;
#pragma unroll
    for (int ctl = 0; ctl < 8; ++ctl) {
        const int ct = wid * 8 + ctl;
        bf16x8 Bh0 = *(const bf16x8*)(Wfh + ((ct * 2 + 0) * 64 + lane) * 8);
        bf16x8 Bl0 = *(const bf16x8*)(Wfl + ((ct * 2 + 0) * 64 + lane) * 8);
        bf16x8 Bh1 = *(const bf16x8*)(Wfh + ((ct * 2 + 1) * 64 + lane) * 8);
        bf16x8 Bl1 = *(const bf16x8*)(Wfl + ((ct * 2 + 1) * 64 + lane) * 8);
#pragma unroll
        for (int rt = 0; rt < 4; ++rt) {
            floatx4 C = {0.f, 0.f, 0.f, 0.f};
            C = MFMA(Ah[rt][0], Bh0, C);
            C = MFMA(Ah[rt][0], Bl0, C);
            C = MFMA(Al[rt][0], Bh0, C);
            C = MFMA(Ah[rt][1], Bh1, C);
            C = MFMA(Ah[rt][1], Bl1, C);
            C = MFMA(Al[rt][1], Bh1, C);
#pragma unroll
            for (int r = 0; r < 4; ++r)
                out[(orow0 + 16 * rt + 4 * lg + r) * HD_ + ct * 16 + lm] = C[r];
        }
    }
}

extern "C" void kernel_launch(void* const* d_in, const int* in_sizes, int n_in,
                              void* d_out, int out_size, void* d_ws, size_t ws_size,
                              hipStream_t stream) {
    const float* x = (const float*)d_in[0];
    const float* W = (const float*)d_in[1];
    unsigned short* wsf = (unsigned short*)d_ws;   // ~12.9 MB used

    k_prep <<<dim3(532), 256, 0, stream>>>(x, W, wsf);
    k_fused<<<dim3(512), 512, 0, stream>>>(wsf, (float*)d_out);
}